// Round 6
// baseline (107.338 us; speedup 1.0000x reference)
//
#include <hip/hip_runtime.h>
#include <hip/hip_fp16.h>

#define NQ     12
#define NPARAM 240       // 12*4*5
#define BLOCK  512
#define NREG   8

typedef float v2f __attribute__((ext_vector_type(2)));
typedef unsigned int h2;     // packed f16 complex: lo=re, hi=im
#define IDH 0x00003C00u      // (1.0, 0.0) in packed f16

// ---- packed f16 complex primitives (v_pk_*_f16, full rate = 2x f32 flops) ----
__device__ __forceinline__ h2 pk_cmul16(h2 a, h2 b) {
    h2 t;
    asm("v_pk_mul_f16 %0, %1, %2 op_sel:[0,0] op_sel_hi:[0,1]\n\t"
        "v_pk_fma_f16 %0, %1, %2, %0 op_sel:[1,1,0] op_sel_hi:[1,0,1] neg_lo:[1,0,0]"
        : "=&v"(t) : "v"(a), "v"(b));
    return t;
}
__device__ __forceinline__ h2 pk_cmac16(h2 t0, h2 a, h2 b) {
    h2 t;
    asm("v_pk_fma_f16 %0, %2, %3, %1 op_sel:[0,0,0] op_sel_hi:[0,1,1]\n\t"
        "v_pk_fma_f16 %0, %2, %3, %0 op_sel:[1,1,0] op_sel_hi:[1,0,1] neg_lo:[1,0,0]"
        : "=&v"(t) : "v"(t0), "v"(a), "v"(b));
    return t;
}
// CRX halfstep: cs2=(c,s): lo = c*sx + s*py ; hi = c*sy - s*px
__device__ __forceinline__ h2 pk_crx16(h2 cs2, h2 s, h2 p) {
    h2 t;
    asm("v_pk_mul_f16 %0, %1, %2 op_sel:[0,0] op_sel_hi:[0,1]\n\t"
        "v_pk_fma_f16 %0, %1, %3, %0 op_sel:[1,1,0] op_sel_hi:[1,0,1] neg_hi:[0,1,0]"
        : "=&v"(t) : "v"(cs2), "v"(s), "v"(p));
    return t;
}
// f32 conj-accumulate for epilogue: acc += conj(s)(.)p
__device__ __forceinline__ v2f pk_cjmac(v2f a0, v2f s, v2f p) {
    v2f t;
    asm("v_pk_fma_f32 %0, %2, %3, %1 op_sel:[0,0,0] op_sel_hi:[0,1,1]\n\t"
        "v_pk_fma_f32 %0, %2, %3, %0 op_sel:[1,1,0] op_sel_hi:[1,0,1] neg_hi:[1,0,0]"
        : "=&v"(t) : "v"(a0), "v"(s), "v"(p));
    return t;
}

__device__ __forceinline__ h2 packh2(float x, float y) {
    return ((h2)__half_as_ushort(__float2half_rn(y)) << 16) |
           (h2)__half_as_ushort(__float2half_rn(x));
}
__device__ __forceinline__ v2f uph2(h2 u) {
    return (v2f){ __half2float(__ushort_as_half((unsigned short)(u & 0xffff))),
                  __half2float(__ushort_as_half((unsigned short)(u >> 16))) };
}

// Storage position p for a qubit:
//   p in [0,3)  -> register bit p of r       : pure VALU
//   p in [3,5)  -> lane bit (p-3), DPP       : pure VALU
//   p in [5,9)  -> lane bit (p-3)            : ds_swizzle / bpermute / buf
//   p in [9,12) -> tid bit (p-3) = wave bit  : ctrl-only (bit select)
//
// R20: 3-window schedule. The layer's 25 gates partition into
//   WX = [D+E of layer l-1 (CRX(8,7)..(0,11)), A of layer l (U0,F01..F34)]
//   WY = [B: F45..F89],  WZ = [C: F(9,10),F(10,11),CRX(11,0),(11,10),(10,9),(9,8)]
// WX's 9 targets {11,0..7} exactly fill pos0-8; ctrls 8,9,10 live at wave
// bits (ctrl needs only a tid bit). -> 3 remaps/layer = 12 total (was 16).
// Maps are co-designed so every remap read is bank-conflict-free: >=5 of
// the 6 new lane-bit qubits come from old addr bits 0-4 (lane set
// {0,4,5,6,7} circulates):
//   MX->MY: lane ebits {2,3,4,0,1,7}  (5 in-bank)
//   MY->MZ: lane ebits {3,4,0,1,2,9}  (5 in-bank)
//   MZ->MX: lane ebits {0,1,2,3,4,11} (5 in-bank)
// Ping-pong parity (3 odd remaps/layer): loop body = 2 layers -> 6 remaps
// with PH = 0,1,0,1,0,1, uniform per iteration. Gate order is exactly
// circuit order; matrices and math identical to R19.
//
// Kept from earlier rounds: R14 single-barrier ping-pong remap + folded
// roff immediates; R16 wsum4 truncation (instr removal pays at full
// 8-wave issue rate: 144 instrs ~= 1 us); R18b parallel prologue trig;
// R19 no-stagger (phase-collision theory dead) + ds_swizzle lxor.

constexpr int QMAP[3][12] = {
    // pos:   0   1   2   3   4   5   6   7   8    9  10  11
    /*MX*/ {  1,  2,  3,  0,  4,  5,  6,  7, 11,   8,  9, 10},
    /*MY*/ {  8,  1,  2,  5,  6,  7,  0,  4,  9,   3, 10, 11},
    /*MZ*/ {  9, 10, 11,  0,  4,  5,  6,  7,  8,   1,  2,  3},
};

constexpr int posof(int m, int q) {
    for (int p = 0; p < 12; ++p) if (QMAP[m][p] == q) return p;
    return -1;
}
constexpr int ebit(int p) { return p < 3 ? 9 + p : p - 3; }
constexpr int roff(int MA, int MB, int r) {
    int off = 0;
    for (int p = 0; p < 3; ++p)
        off |= ((r >> p) & 1) << ebit(posof(MA, QMAP[MB][p]));
    return off;
}

template<int MA, int MB>
__device__ __forceinline__ int rbase(int tid) {
    int base = 0;
    #pragma unroll
    for (int p = 3; p < 12; ++p)
        base |= ((tid >> (p - 3)) & 1) << ebit(posof(MA, QMAP[MB][p]));
    return base;
}

// single-barrier ping-pong remap: PH selects the 16 KB half-buffer
template<int MA, int MB, int PH>
__device__ __forceinline__ void remap(h2* st, int tid, h2* bufh, int base) {
    h2* bp = bufh + PH * (NREG * BLOCK);
    #pragma unroll
    for (int r = 0; r < NREG; ++r) bp[r * BLOCK + tid] = st[r];
    __syncthreads();
    #pragma unroll
    for (int r = 0; r < NREG; ++r) st[r] = bp[base + roff(MA, MB, r)];
}

template<int LM>
__device__ __forceinline__ int lxori(int v) {
    if constexpr (LM == 1) {        // quad_perm [1,0,3,2] = xor 1, VALU pipe
        return __builtin_amdgcn_update_dpp(v, v, 0xB1, 0xF, 0xF, false);
    } else if constexpr (LM == 2) { // quad_perm [2,3,0,1] = xor 2, VALU pipe
        return __builtin_amdgcn_update_dpp(v, v, 0x4E, 0xF, 0xF, false);
    } else if constexpr (LM == 4) { // ds_swizzle BitMode xor-4, no addr VGPR
        return __builtin_amdgcn_ds_swizzle(v, 0x101F);
    } else if constexpr (LM == 8) {
        return __builtin_amdgcn_ds_swizzle(v, 0x201F);
    } else if constexpr (LM == 16) {
        return __builtin_amdgcn_ds_swizzle(v, 0x401F);
    } else {
        return __shfl_xor(v, LM, 64);
    }
}
template<int LM>
__device__ __forceinline__ h2 lxor_h(h2 v) { return (h2)lxori<LM>((int)v); }
template<int LM>
__device__ __forceinline__ v2f lxor2(v2f v) {
    v2f p = { __int_as_float(lxori<LM>(__float_as_int(v.x))),
              __int_as_float(lxori<LM>(__float_as_int(v.y))) };
    return p;
}

// truncated DPP reduction: 4 row_shr steps; lane 15 of each 16-lane row
// holds that row's sum. Cross-row + cross-wave handled via redbuf.
__device__ __forceinline__ float wsum4(float x) {
    x += __int_as_float(__builtin_amdgcn_update_dpp(0, __float_as_int(x), 0x111, 0xF, 0xF, true));
    x += __int_as_float(__builtin_amdgcn_update_dpp(0, __float_as_int(x), 0x112, 0xF, 0xF, true));
    x += __int_as_float(__builtin_amdgcn_update_dpp(0, __float_as_int(x), 0x114, 0xF, 0xF, true));
    x += __int_as_float(__builtin_amdgcn_update_dpp(0, __float_as_int(x), 0x118, 0xF, 0xF, true));
    return x;
}

__device__ __forceinline__ float2 cmulf(float2 a, float2 b) {
    return make_float2(a.x*b.x - a.y*b.y, a.x*b.y + a.y*b.x);
}

// plain 1q gate at position P
template<int P>
__device__ __forceinline__ void apply1q(h2* st, int tid, const h2* m) {
    h2 u00 = m[0], u01 = m[1], u10 = m[2], u11 = m[3];
    if constexpr (P < 3) {
        #pragma unroll
        for (int r = 0; r < NREG; ++r) {
            if ((r >> P) & 1) continue;
            int r1 = r | (1 << P);
            h2 s0 = st[r], s1 = st[r1];
            st[r]  = pk_cmac16(pk_cmul16(u00, s0), u01, s1);
            st[r1] = pk_cmac16(pk_cmul16(u10, s0), u11, s1);
        }
    } else {
        constexpr int LM = 1 << (P - 3);
        int bit = (tid >> (P - 3)) & 1;
        h2 d = bit ? u11 : u00;
        h2 o = bit ? u10 : u01;
        #pragma unroll
        for (int r = 0; r < NREG; ++r) {
            h2 p = lxor_h<LM>(st[r]);
            st[r] = pk_cmac16(pk_cmul16(d, st[r]), o, p);
        }
    }
}

// fused ring1 gate: A (ctrl=0) / B = RX*A (ctrl=1)
template<int PC, int PT>
__device__ __forceinline__ void fgate(h2* st, int tid, const h2* A, const h2* B) {
    h2 a00 = A[0], a01 = A[1], a10 = A[2], a11 = A[3];
    h2 b00 = B[0], b01 = B[1], b10 = B[2], b11 = B[3];
    if constexpr (PT < 3) {
        if constexpr (PC < 3) {
            #pragma unroll
            for (int r = 0; r < NREG; ++r) {
                if ((r >> PT) & 1) continue;
                const bool uB = (r >> PC) & 1;               // compile-time
                h2 m00 = uB ? b00 : a00, m01 = uB ? b01 : a01;
                h2 m10 = uB ? b10 : a10, m11 = uB ? b11 : a11;
                int r1 = r | (1 << PT);
                h2 s0 = st[r], s1 = st[r1];
                st[r]  = pk_cmac16(pk_cmul16(m00, s0), m01, s1);
                st[r1] = pk_cmac16(pk_cmul16(m10, s0), m11, s1);
            }
        } else {
            int cbit = (tid >> (PC - 3)) & 1;
            h2 m00 = cbit ? b00 : a00, m01 = cbit ? b01 : a01;
            h2 m10 = cbit ? b10 : a10, m11 = cbit ? b11 : a11;
            #pragma unroll
            for (int r = 0; r < NREG; ++r) {
                if ((r >> PT) & 1) continue;
                int r1 = r | (1 << PT);
                h2 s0 = st[r], s1 = st[r1];
                st[r]  = pk_cmac16(pk_cmul16(m00, s0), m01, s1);
                st[r1] = pk_cmac16(pk_cmul16(m10, s0), m11, s1);
            }
        }
    } else {
        constexpr int LM = 1 << (PT - 3);
        int tbit = (tid >> (PT - 3)) & 1;
        h2 dA = tbit ? a11 : a00, oA = tbit ? a10 : a01;
        h2 dB = tbit ? b11 : b00, oB = tbit ? b10 : b01;
        if constexpr (PC < 3) {
            #pragma unroll
            for (int r = 0; r < NREG; ++r) {
                const bool uB = (r >> PC) & 1;               // compile-time
                h2 d = uB ? dB : dA, o = uB ? oB : oA;
                h2 p = lxor_h<LM>(st[r]);
                st[r] = pk_cmac16(pk_cmul16(d, st[r]), o, p);
            }
        } else {
            int cbit = (tid >> (PC - 3)) & 1;
            h2 d = cbit ? dB : dA, o = cbit ? oB : oA;
            #pragma unroll
            for (int r = 0; r < NREG; ++r) {
                h2 p = lxor_h<LM>(st[r]);
                st[r] = pk_cmac16(pk_cmul16(d, st[r]), o, p);
            }
        }
    }
}

// CRX(ctrl at PC, tgt at PT)
template<int PC, int PT>
__device__ __forceinline__ void applyCRX(h2* st, int tid, const h2* cs) {
    h2 cs2 = cs[0];                      // packed (cos, sin)
    if constexpr (PT < 3) {
        if constexpr (PC < 3) {
            #pragma unroll
            for (int r = 0; r < NREG; ++r) {
                if (!((r >> PC) & 1) || ((r >> PT) & 1)) continue;
                int r1 = r | (1 << PT);
                h2 s0 = st[r], s1 = st[r1];
                st[r]  = pk_crx16(cs2, s0, s1);
                st[r1] = pk_crx16(cs2, s1, s0);
            }
        } else {
            int apply = (tid >> (PC - 3)) & 1;
            h2 cse = apply ? cs2 : IDH;
            #pragma unroll
            for (int r = 0; r < NREG; ++r) {
                if ((r >> PT) & 1) continue;
                int r1 = r | (1 << PT);
                h2 s0 = st[r], s1 = st[r1];
                st[r]  = pk_crx16(cse, s0, s1);
                st[r1] = pk_crx16(cse, s1, s0);
            }
        }
    } else {
        constexpr int LM = 1 << (PT - 3);
        if constexpr (PC < 3) {
            #pragma unroll
            for (int r = 0; r < NREG; ++r) {
                if (!((r >> PC) & 1)) continue;
                h2 p = lxor_h<LM>(st[r]);
                st[r] = pk_crx16(cs2, st[r], p);
            }
        } else {
            int apply = (tid >> (PC - 3)) & 1;
            h2 cse = apply ? cs2 : IDH;
            #pragma unroll
            for (int r = 0; r < NREG; ++r) {
                h2 p = lxor_h<LM>(st[r]);
                st[r] = pk_crx16(cse, st[r], p);
            }
        }
    }
}

// ---- window gate groups (positions per QMAP above) ----
// WX under MX: q1@0,q2@1,q3@2, q0@3,q4@4, q5@5,q6@6,q7@7,q11@8 | q8,q9,q10 wave
__device__ __forceinline__ void Agates(h2* st, int tid, const h2* ma, const h2* mb) {
    apply1q<3>(st, tid, ma + 0 * 4);                 // U(q0) @3
    fgate<3, 0>(st, tid, ma + 1 * 4, mb + 0 * 4);    // F(0,1)
    fgate<0, 1>(st, tid, ma + 2 * 4, mb + 1 * 4);    // F(1,2)
    fgate<1, 2>(st, tid, ma + 3 * 4, mb + 2 * 4);    // F(2,3)
    fgate<2, 4>(st, tid, ma + 4 * 4, mb + 3 * 4);    // F(3,4)
}
__device__ __forceinline__ void DEgates(h2* st, int tid, const h2* cl) {
    applyCRX<9, 7>(st, tid, cl + 15);                // (8,7)  ctrl wave
    applyCRX<7, 6>(st, tid, cl + 16);                // (7,6)
    applyCRX<6, 5>(st, tid, cl + 17);                // (6,5)
    applyCRX<5, 4>(st, tid, cl + 18);                // (5,4)
    applyCRX<4, 2>(st, tid, cl + 19);                // (4,3)
    applyCRX<2, 1>(st, tid, cl + 20);                // (3,2)
    applyCRX<1, 0>(st, tid, cl + 21);                // (2,1)
    applyCRX<0, 3>(st, tid, cl + 22);                // (1,0)
    applyCRX<3, 8>(st, tid, cl + 23);                // (0,11)
}
// WY under MY: q8@0,q1@1,q2@2, q5@3,q6@4, q7@5,q0@6,q4@7,q9@8 | q3,q10,q11 wave
__device__ __forceinline__ void Bgates(h2* st, int tid, const h2* ma, const h2* mb) {
    fgate<7, 3>(st, tid, ma + 5 * 4, mb + 4 * 4);    // F(4,5)
    fgate<3, 4>(st, tid, ma + 6 * 4, mb + 5 * 4);    // F(5,6)
    fgate<4, 5>(st, tid, ma + 7 * 4, mb + 6 * 4);    // F(6,7)
    fgate<5, 0>(st, tid, ma + 8 * 4, mb + 7 * 4);    // F(7,8)
    fgate<0, 8>(st, tid, ma + 9 * 4, mb + 8 * 4);    // F(8,9)
}
// WZ under MZ: q9@0,q10@1,q11@2, q0@3,q4@4, q5@5,q6@6,q7@7,q8@8 | q1,q2,q3 wave
__device__ __forceinline__ void Cgates(h2* st, int tid, const h2* ma, const h2* mb, const h2* cl) {
    fgate<0, 1>(st, tid, ma + 10 * 4, mb + 9 * 4);   // F(9,10)
    fgate<1, 2>(st, tid, ma + 11 * 4, mb + 10 * 4);  // F(10,11)
    applyCRX<2, 3>(st, tid, cl + 11);                // CRX(11,0)
    applyCRX<2, 1>(st, tid, cl + 12);                // (11,10)
    applyCRX<1, 0>(st, tid, cl + 13);                // (10,9)
    applyCRX<0, 8>(st, tid, cl + 14);                // (9,8)
}

__global__ __launch_bounds__(BLOCK)
void qfe_kernel(const float* __restrict__ params,
                const float* __restrict__ inputs,
                float* __restrict__ out) {
    const int b    = blockIdx.x;
    const int tid  = threadIdx.x;
    const int lane = tid & 63;

    __shared__ v2f buf[NREG * BLOCK];      // 32 KB: 2x16KB f16 ping-pong / f32 epilogue
    h2* bufh = (h2*)buf;
    __shared__ __align__(16) h2 mA[4 * 12 * 4];   // packed f16 matrices
    __shared__ __align__(16) h2 mB[4 * 11 * 4];
    __shared__ __align__(16) h2 mcrx[4 * 24];     // packed (cos,sin)
    __shared__ float  redbuf[32][36];             // epilogue row-partials; prologue cs table

    // parallel trig table (R18b). Aliases redbuf.
    float2* cs = (float2*)redbuf;
    if (tid < 240) {
        float a = params[b * NPARAM + tid] * 0.5f;
        cs[tid] = make_float2(cosf(a), sinf(a));
    } else if (tid < 252) {
        float e = inputs[b * NQ + (tid - 240)] * 0.5f;
        cs[tid] = make_float2(cosf(e), sinf(e));
    }
    __syncthreads();

    if (tid < 48) {
        int l = tid / 12, q = tid % 12;
        const float2 vx = cs[l * 60 + q * 3 + 0];
        const float2 vy = cs[l * 60 + q * 3 + 1];
        const float2 vz = cs[l * 60 + q * 3 + 2];
        float cx = vx.x, sx = vx.y;
        float cy = vy.x, sy = vy.y;
        float cz = vz.x, sz = vz.y;
        float2 a00 = make_float2( cy*cx,  sy*sx);
        float2 a01 = make_float2(-sy*cx, -cy*sx);
        float2 a10 = make_float2( sy*cx, -cy*sx);
        float2 a11 = make_float2( cy*cx, -sy*sx);
        float2 e0 = make_float2(cz, -sz);
        float2 e1 = make_float2(cz,  sz);
        float2 u00 = cmulf(e0, a00), u01 = cmulf(e0, a01);
        float2 u10 = cmulf(e1, a10), u11 = cmulf(e1, a11);
        if (l == 0) {   // fold RY input embedding
            float ce = cs[240 + q].x, se = cs[240 + q].y;
            float2 v00 = make_float2(u00.x*ce + u01.x*se, u00.y*ce + u01.y*se);
            float2 v01 = make_float2(-u00.x*se + u01.x*ce, -u00.y*se + u01.y*ce);
            float2 v10 = make_float2(u10.x*ce + u11.x*se, u10.y*ce + u11.y*se);
            float2 v11 = make_float2(-u10.x*se + u11.x*ce, -u10.y*se + u11.y*ce);
            u00 = v00; u01 = v01; u10 = v10; u11 = v11;
        }
        h2* m = &mA[(l * 12 + q) * 4];
        m[0] = packh2(u00.x, u00.y); m[1] = packh2(u01.x, u01.y);
        m[2] = packh2(u10.x, u10.y); m[3] = packh2(u11.x, u11.y);
    }
    if (tid >= 64 && tid < 160) {   // mcrx from cs table (independent of mA)
        int k2 = tid - 64;
        int l = k2 / 24, k = k2 % 24;
        float2 v = cs[l * 60 + 36 + k];
        mcrx[l * 24 + k] = packh2(v.x, v.y);
    }
    __syncthreads();
    if (tid < 44) {       // B(l,j) = RX(theta_ring1_j) * U(l, j+1)
        int l = tid / 11, j = tid % 11;
        const h2* U = &mA[(l * 12 + (j + 1)) * 4];
        v2f u00 = uph2(U[0]), u01 = uph2(U[1]), u10 = uph2(U[2]), u11 = uph2(U[3]);
        v2f csv = uph2(mcrx[l * 24 + j]);
        float c = csv.x, s = csv.y;
        h2* Bm = &mB[(l * 11 + j) * 4];
        Bm[0] = packh2( c*u00.x + s*u10.y,  c*u00.y - s*u10.x);
        Bm[1] = packh2( c*u01.x + s*u11.y,  c*u01.y - s*u11.x);
        Bm[2] = packh2( s*u00.y + c*u10.x, -s*u00.x + c*u10.y);
        Bm[3] = packh2( s*u01.y + c*u11.x, -s*u01.x + c*u11.y);
    }
    __syncthreads();

    h2 st[NREG];
    #pragma unroll
    for (int r = 0; r < NREG; ++r) st[r] = 0u;
    if (tid == 0) st[0] = IDH;            // |0..0> is map-independent

    const int rb01 = rbase<0,1>(tid);
    const int rb12 = rbase<1,2>(tid);
    const int rb20 = rbase<2,0>(tid);

    // A(0) under MX, then 2-layer loop body (6 remaps, PH=0,1,0,1,0,1)
    Agates(st, tid, mA, mB);
    #pragma unroll 1
    for (int ll = 0; ll < 2; ++ll) {
        const int l0 = 2 * ll, l1 = 2 * ll + 1;
        const h2* ma0 = mA + l0 * 48;  const h2* mb0 = mB + l0 * 44;  const h2* cl0 = mcrx + l0 * 24;
        const h2* ma1 = mA + l1 * 48;  const h2* mb1 = mB + l1 * 44;  const h2* cl1 = mcrx + l1 * 24;
        // layer l0
        remap<0, 1, 0>(st, tid, bufh, rb01);
        Bgates(st, tid, ma0, mb0);
        remap<1, 2, 1>(st, tid, bufh, rb12);
        Cgates(st, tid, ma0, mb0, cl0);
        remap<2, 0, 0>(st, tid, bufh, rb20);
        DEgates(st, tid, cl0);
        Agates(st, tid, ma1, mb1);
        // layer l1
        remap<0, 1, 1>(st, tid, bufh, rb01);
        Bgates(st, tid, ma1, mb1);
        remap<1, 2, 0>(st, tid, bufh, rb12);
        Cgates(st, tid, ma1, mb1, cl1);
        remap<2, 0, 1>(st, tid, bufh, rb20);
        DEgates(st, tid, cl1);
        if (ll == 0) Agates(st, tid, mA + 2 * 48, mB + 2 * 44);   // A(2)
    }

    // ---- epilogue (f32) under MX ----
    // pos->qubit: 0->1, 1->2, 2->3, 3->0, 4->4, 5->5, 6->6, 7->7, 8->11,
    //             9->8, 10->9, 11->10
    v2f stf[NREG];
    #pragma unroll
    for (int r = 0; r < NREG; ++r) stf[r] = uph2(st[r]);

    float nn[NREG];
    #pragma unroll
    for (int r = 0; r < NREG; ++r) nn[r] = stf[r].x*stf[r].x + stf[r].y*stf[r].y;
    float T  = ((nn[0]+nn[1])+(nn[2]+nn[3])) + ((nn[4]+nn[5])+(nn[6]+nn[7]));
    float Z0 = ((nn[0]-nn[1])+(nn[2]-nn[3])) + ((nn[4]-nn[5])+(nn[6]-nn[7]));
    float Z1 = ((nn[0]+nn[1])-(nn[2]+nn[3])) + ((nn[4]+nn[5])-(nn[6]+nn[7]));
    float Z2 = ((nn[0]+nn[1])+(nn[2]+nn[3])) - ((nn[4]+nn[5])+(nn[6]+nn[7]));

    __syncthreads();                       // WAR vs last remap reads
    #pragma unroll
    for (int r = 0; r < NREG; ++r) buf[r * BLOCK + tid] = stf[r];   // f32 layout
    __syncthreads();

    const int row16 = (tid >> 4);                 // 0..31: 16-lane row index
    const bool isred = (lane & 15) == 15;         // row-sum holder lane
    const float Tsum = wsum4(T);                  // shared row-sum of |psi|^2

#define EXP_REG(q, B, ZV) { \
    v2f acc = {0.f, 0.f}; \
    _Pragma("unroll") \
    for (int r = 0; r < NREG; ++r) { \
        if ((r >> (B)) & 1) continue; \
        acc = pk_cjmac(acc, stf[r], stf[r | (1 << (B))]); \
    } \
    float X = wsum4(2.f*acc.x), Y = wsum4(2.f*acc.y), Z = wsum4(ZV); \
    if (isred) { redbuf[row16][(q)] = X; redbuf[row16][12+(q)] = Y; redbuf[row16][24+(q)] = Z; } }

#define EXP_DPP(q, LM, TB) { \
    v2f acc = {0.f, 0.f}; \
    _Pragma("unroll") \
    for (int r = 0; r < NREG; ++r) { \
        v2f p = lxor2<LM>(stf[r]); \
        acc = pk_cjmac(acc, stf[r], p); \
    } \
    float zs = ((tid >> (TB)) & 1) ? -1.f : 1.f; \
    float X = wsum4(acc.x), Y = wsum4(zs*acc.y), Z = wsum4(zs*T); \
    if (isred) { redbuf[row16][(q)] = X; redbuf[row16][12+(q)] = Y; redbuf[row16][24+(q)] = Z; } }

// TB < 4: sign varies inside the 16-lane row -> full wsum4 on zs*T
#define EXP_BUF(q, XM, TB) { \
    v2f acc = {0.f, 0.f}; \
    int pt = tid ^ (XM); \
    _Pragma("unroll") \
    for (int r = 0; r < NREG; ++r) { \
        acc = pk_cjmac(acc, stf[r], buf[r * BLOCK + pt]); \
    } \
    float zs = ((tid >> (TB)) & 1) ? -1.f : 1.f; \
    float X = wsum4(acc.x), Y = wsum4(zs*acc.y), Z = wsum4(zs*T); \
    if (isred) { redbuf[row16][(q)] = X; redbuf[row16][12+(q)] = Y; redbuf[row16][24+(q)] = Z; } }

// TB >= 4: sign is row-uniform -> Z = zs * Tsum (no wsum4)
#define EXP_BUF_HI(q, XM, TB) { \
    v2f acc = {0.f, 0.f}; \
    int pt = tid ^ (XM); \
    _Pragma("unroll") \
    for (int r = 0; r < NREG; ++r) { \
        acc = pk_cjmac(acc, stf[r], buf[r * BLOCK + pt]); \
    } \
    float zs = ((tid >> (TB)) & 1) ? -1.f : 1.f; \
    float X = wsum4(acc.x), Y = wsum4(zs*acc.y), Z = zs * Tsum; \
    if (isred) { redbuf[row16][(q)] = X; redbuf[row16][12+(q)] = Y; redbuf[row16][24+(q)] = Z; } }

    EXP_REG(1, 0, Z0)  EXP_REG(2, 1, Z1)  EXP_REG(3, 2, Z2)
    EXP_DPP(0, 1, 0)   EXP_DPP(4, 2, 1)
    EXP_BUF(5, 4, 2)   EXP_BUF(6, 8, 3)
    EXP_BUF_HI(7, 16, 4)   EXP_BUF_HI(11, 32, 5)
    EXP_BUF_HI(8, 64, 6)   EXP_BUF_HI(9, 128, 7)  EXP_BUF_HI(10, 256, 8)

    __syncthreads();
    if (tid < 36) {
        float acc = 0.f;
        #pragma unroll
        for (int i = 0; i < 32; ++i) acc += redbuf[i][tid];
        out[b * 36 + tid] = acc;
    }
}

extern "C" void kernel_launch(void* const* d_in, const int* in_sizes, int n_in,
                              void* d_out, int out_size, void* d_ws, size_t ws_size,
                              hipStream_t stream) {
    const float* params = (const float*)d_in[0];   // (1024, 240) float32
    const float* inputs = (const float*)d_in[1];   // (1024, 12)  float32
    float* out = (float*)d_out;                    // (1024, 36)  float32
    qfe_kernel<<<1024, BLOCK, 0, stream>>>(params, inputs, out);
}

// Round 7
// 105.395 us; speedup vs baseline: 1.0184x; 1.0184x over previous
//
#include <hip/hip_runtime.h>
#include <hip/hip_fp16.h>

#define NQ     12
#define NPARAM 240       // 12*4*5
#define BLOCK  512
#define NREG   8

typedef float v2f __attribute__((ext_vector_type(2)));
typedef unsigned int h2;     // packed f16 complex: lo=re, hi=im
#define IDH 0x00003C00u      // (1.0, 0.0) in packed f16

// ---- packed f16 complex primitives (v_pk_*_f16, full rate = 2x f32 flops) ----
__device__ __forceinline__ h2 pk_cmul16(h2 a, h2 b) {
    h2 t;
    asm("v_pk_mul_f16 %0, %1, %2 op_sel:[0,0] op_sel_hi:[0,1]\n\t"
        "v_pk_fma_f16 %0, %1, %2, %0 op_sel:[1,1,0] op_sel_hi:[1,0,1] neg_lo:[1,0,0]"
        : "=&v"(t) : "v"(a), "v"(b));
    return t;
}
__device__ __forceinline__ h2 pk_cmac16(h2 t0, h2 a, h2 b) {
    h2 t;
    asm("v_pk_fma_f16 %0, %2, %3, %1 op_sel:[0,0,0] op_sel_hi:[0,1,1]\n\t"
        "v_pk_fma_f16 %0, %2, %3, %0 op_sel:[1,1,0] op_sel_hi:[1,0,1] neg_lo:[1,0,0]"
        : "=&v"(t) : "v"(t0), "v"(a), "v"(b));
    return t;
}
// CRX halfstep: cs2=(c,s): lo = c*sx + s*py ; hi = c*sy - s*px
__device__ __forceinline__ h2 pk_crx16(h2 cs2, h2 s, h2 p) {
    h2 t;
    asm("v_pk_mul_f16 %0, %1, %2 op_sel:[0,0] op_sel_hi:[0,1]\n\t"
        "v_pk_fma_f16 %0, %1, %3, %0 op_sel:[1,1,0] op_sel_hi:[1,0,1] neg_hi:[0,1,0]"
        : "=&v"(t) : "v"(cs2), "v"(s), "v"(p));
    return t;
}
// f32 conj-accumulate for epilogue: acc += conj(s)(.)p
__device__ __forceinline__ v2f pk_cjmac(v2f a0, v2f s, v2f p) {
    v2f t;
    asm("v_pk_fma_f32 %0, %2, %3, %1 op_sel:[0,0,0] op_sel_hi:[0,1,1]\n\t"
        "v_pk_fma_f32 %0, %2, %3, %0 op_sel:[1,1,0] op_sel_hi:[1,0,1] neg_hi:[1,0,0]"
        : "=&v"(t) : "v"(a0), "v"(s), "v"(p));
    return t;
}

__device__ __forceinline__ h2 packh2(float x, float y) {
    return ((h2)__half_as_ushort(__float2half_rn(y)) << 16) |
           (h2)__half_as_ushort(__float2half_rn(x));
}
__device__ __forceinline__ v2f uph2(h2 u) {
    return (v2f){ __half2float(__ushort_as_half((unsigned short)(u & 0xffff))),
                  __half2float(__ushort_as_half((unsigned short)(u >> 16))) };
}

// Storage position p for a qubit:
//   p in [0,3)  -> register bit p of r       : pure VALU
//   p in [3,5)  -> lane bit (p-3), DPP       : pure VALU
//   p in [5,9)  -> lane bit (p-3)            : ds_swizzle / bpermute / buf
//   p in [9,12) -> tid bit (p-3) = wave bit  : ctrl-only (bit select)
// 4-map cycle M4 -> M1 -> M2 -> M3 -> M4 (16 remaps). Init/epilogue under M4.
//
// R14: ping-pong remap buffers -> 1 barrier per remap; read address = base +
// roff (disjoint bits) so roff folds into the ds_read immediate.
//
// R15/R16: M1->M2 / M2->M3 remap reads are 4-way bank-conflicted; XOR
// swizzle fixed the counter (2.10M -> 1.05M floor) but cost more VALU/VGPR
// than the <1us the conflicts cost -> reverted. ~2.1M is benign here.
//
// R16: epilogue wsum truncated to 4 DPP steps; cross-row reduction folded
// into redbuf[32][36]. CALIBRATION: instruction removal pays at the full
// 8-wave/SIMD issue rate (144 instrs ~= 1 us).
//
// R17-R19: block phase stagger tested and REMOVED (net <= 0: its start-tail
// cancels any steady-state gain; phase-collision theory dead). Parallel
// prologue trig + ds_swizzle lxor kept. R5 state = 59.3 us.
//
// R20 (REVERTED): 3-window/12-remap schedule. Bank conflicts -> ~0 as
// designed, but WX's 9-targets-in-pos0-8 forced 7 LDS-pipe gates/layer
// (4 ds_swizzle + 3 bpermute-xor32) vs this schedule's 1 -> +3.4 us.
// LESSON: two cost currencies - VALU instrs AND LDS-pipe ops. This 4-window
// schedule is provably minimal (ring1+ring2 each span 12 targets; <=6
// distinct targets/window => 4 windows/layer) AND has near-minimal LDS
// gate ops (16 reg + 8 DPP + 1 swizzle per layer). Do not re-attempt
// window-count reduction without a placement keeping expensive gates <= 2.

constexpr int QMAP[5][12] = {
    // pos:   0   1   2   3   4    5   6   7   8    9  10  11
    /*M0*/ {  0,  1,  2,  3,  4,  10, 11,  9,  8,   5,  6,  7},   // unused
    /*M1*/ {  5,  6,  7,  8,  9,   3,  4, 10, 11,   0,  1,  2},
    /*M2*/ { 10, 11,  0,  9,  8,   3,  4,  5,  6,   1,  2,  7},
    /*M3*/ {  7,  6,  5,  4,  3,   9,  8, 10, 11,   0,  1,  2},
    /*M4*/ {  2,  1,  0, 11,  4,   3,  9,  8, 10,   5,  6,  7},
};

constexpr int posof(int m, int q) {
    for (int p = 0; p < 12; ++p) if (QMAP[m][p] == q) return p;
    return -1;
}
constexpr int ebit(int p) { return p < 3 ? 9 + p : p - 3; }
constexpr int roff(int MA, int MB, int r) {
    int off = 0;
    for (int p = 0; p < 3; ++p)
        off |= ((r >> p) & 1) << ebit(posof(MA, QMAP[MB][p]));
    return off;
}

template<int MA, int MB>
__device__ __forceinline__ int rbase(int tid) {
    int base = 0;
    #pragma unroll
    for (int p = 3; p < 12; ++p)
        base |= ((tid >> (p - 3)) & 1) << ebit(posof(MA, QMAP[MB][p]));
    return base;
}

// single-barrier ping-pong remap: PH selects the 16 KB half-buffer
template<int MA, int MB, int PH>
__device__ __forceinline__ void remap(h2* st, int tid, h2* bufh, int base) {
    h2* bp = bufh + PH * (NREG * BLOCK);
    #pragma unroll
    for (int r = 0; r < NREG; ++r) bp[r * BLOCK + tid] = st[r];
    __syncthreads();
    #pragma unroll
    for (int r = 0; r < NREG; ++r) st[r] = bp[base + roff(MA, MB, r)];
}

template<int LM>
__device__ __forceinline__ int lxori(int v) {
    if constexpr (LM == 1) {        // quad_perm [1,0,3,2] = xor 1, VALU pipe
        return __builtin_amdgcn_update_dpp(v, v, 0xB1, 0xF, 0xF, false);
    } else if constexpr (LM == 2) { // quad_perm [2,3,0,1] = xor 2, VALU pipe
        return __builtin_amdgcn_update_dpp(v, v, 0x4E, 0xF, 0xF, false);
    } else if constexpr (LM == 4) { // ds_swizzle BitMode xor-4, no addr VGPR
        return __builtin_amdgcn_ds_swizzle(v, 0x101F);
    } else if constexpr (LM == 8) {
        return __builtin_amdgcn_ds_swizzle(v, 0x201F);
    } else if constexpr (LM == 16) {
        return __builtin_amdgcn_ds_swizzle(v, 0x401F);
    } else {
        return __shfl_xor(v, LM, 64);
    }
}
template<int LM>
__device__ __forceinline__ h2 lxor_h(h2 v) { return (h2)lxori<LM>((int)v); }
template<int LM>
__device__ __forceinline__ v2f lxor2(v2f v) {
    v2f p = { __int_as_float(lxori<LM>(__float_as_int(v.x))),
              __int_as_float(lxori<LM>(__float_as_int(v.y))) };
    return p;
}

// truncated DPP reduction: 4 row_shr steps; lane 15 of each 16-lane row
// holds that row's sum. Cross-row + cross-wave handled via redbuf.
__device__ __forceinline__ float wsum4(float x) {
    x += __int_as_float(__builtin_amdgcn_update_dpp(0, __float_as_int(x), 0x111, 0xF, 0xF, true));
    x += __int_as_float(__builtin_amdgcn_update_dpp(0, __float_as_int(x), 0x112, 0xF, 0xF, true));
    x += __int_as_float(__builtin_amdgcn_update_dpp(0, __float_as_int(x), 0x114, 0xF, 0xF, true));
    x += __int_as_float(__builtin_amdgcn_update_dpp(0, __float_as_int(x), 0x118, 0xF, 0xF, true));
    return x;
}

__device__ __forceinline__ float2 cmulf(float2 a, float2 b) {
    return make_float2(a.x*b.x - a.y*b.y, a.x*b.y + a.y*b.x);
}

// plain 1q gate at position P
template<int P>
__device__ __forceinline__ void apply1q(h2* st, int tid, const h2* m) {
    h2 u00 = m[0], u01 = m[1], u10 = m[2], u11 = m[3];
    if constexpr (P < 3) {
        #pragma unroll
        for (int r = 0; r < NREG; ++r) {
            if ((r >> P) & 1) continue;
            int r1 = r | (1 << P);
            h2 s0 = st[r], s1 = st[r1];
            st[r]  = pk_cmac16(pk_cmul16(u00, s0), u01, s1);
            st[r1] = pk_cmac16(pk_cmul16(u10, s0), u11, s1);
        }
    } else {
        constexpr int LM = 1 << (P - 3);
        int bit = (tid >> (P - 3)) & 1;
        h2 d = bit ? u11 : u00;
        h2 o = bit ? u10 : u01;
        #pragma unroll
        for (int r = 0; r < NREG; ++r) {
            h2 p = lxor_h<LM>(st[r]);
            st[r] = pk_cmac16(pk_cmul16(d, st[r]), o, p);
        }
    }
}

// fused ring1 gate: A (ctrl=0) / B = RX*A (ctrl=1)
template<int PC, int PT>
__device__ __forceinline__ void fgate(h2* st, int tid, const h2* A, const h2* B) {
    h2 a00 = A[0], a01 = A[1], a10 = A[2], a11 = A[3];
    h2 b00 = B[0], b01 = B[1], b10 = B[2], b11 = B[3];
    if constexpr (PT < 3) {
        if constexpr (PC < 3) {
            #pragma unroll
            for (int r = 0; r < NREG; ++r) {
                if ((r >> PT) & 1) continue;
                const bool uB = (r >> PC) & 1;               // compile-time
                h2 m00 = uB ? b00 : a00, m01 = uB ? b01 : a01;
                h2 m10 = uB ? b10 : a10, m11 = uB ? b11 : a11;
                int r1 = r | (1 << PT);
                h2 s0 = st[r], s1 = st[r1];
                st[r]  = pk_cmac16(pk_cmul16(m00, s0), m01, s1);
                st[r1] = pk_cmac16(pk_cmul16(m10, s0), m11, s1);
            }
        } else {
            int cbit = (tid >> (PC - 3)) & 1;
            h2 m00 = cbit ? b00 : a00, m01 = cbit ? b01 : a01;
            h2 m10 = cbit ? b10 : a10, m11 = cbit ? b11 : a11;
            #pragma unroll
            for (int r = 0; r < NREG; ++r) {
                if ((r >> PT) & 1) continue;
                int r1 = r | (1 << PT);
                h2 s0 = st[r], s1 = st[r1];
                st[r]  = pk_cmac16(pk_cmul16(m00, s0), m01, s1);
                st[r1] = pk_cmac16(pk_cmul16(m10, s0), m11, s1);
            }
        }
    } else {
        constexpr int LM = 1 << (PT - 3);
        int tbit = (tid >> (PT - 3)) & 1;
        h2 dA = tbit ? a11 : a00, oA = tbit ? a10 : a01;
        h2 dB = tbit ? b11 : b00, oB = tbit ? b10 : b01;
        if constexpr (PC < 3) {
            #pragma unroll
            for (int r = 0; r < NREG; ++r) {
                const bool uB = (r >> PC) & 1;               // compile-time
                h2 d = uB ? dB : dA, o = uB ? oB : oA;
                h2 p = lxor_h<LM>(st[r]);
                st[r] = pk_cmac16(pk_cmul16(d, st[r]), o, p);
            }
        } else {
            int cbit = (tid >> (PC - 3)) & 1;
            h2 d = cbit ? dB : dA, o = cbit ? oB : oA;
            #pragma unroll
            for (int r = 0; r < NREG; ++r) {
                h2 p = lxor_h<LM>(st[r]);
                st[r] = pk_cmac16(pk_cmul16(d, st[r]), o, p);
            }
        }
    }
}

// CRX(ctrl at PC, tgt at PT)
template<int PC, int PT>
__device__ __forceinline__ void applyCRX(h2* st, int tid, const h2* cs) {
    h2 cs2 = cs[0];                      // packed (cos, sin)
    if constexpr (PT < 3) {
        if constexpr (PC < 3) {
            #pragma unroll
            for (int r = 0; r < NREG; ++r) {
                if (!((r >> PC) & 1) || ((r >> PT) & 1)) continue;
                int r1 = r | (1 << PT);
                h2 s0 = st[r], s1 = st[r1];
                st[r]  = pk_crx16(cs2, s0, s1);
                st[r1] = pk_crx16(cs2, s1, s0);
            }
        } else {
            int apply = (tid >> (PC - 3)) & 1;
            h2 cse = apply ? cs2 : IDH;
            #pragma unroll
            for (int r = 0; r < NREG; ++r) {
                if ((r >> PT) & 1) continue;
                int r1 = r | (1 << PT);
                h2 s0 = st[r], s1 = st[r1];
                st[r]  = pk_crx16(cse, s0, s1);
                st[r1] = pk_crx16(cse, s1, s0);
            }
        }
    } else {
        constexpr int LM = 1 << (PT - 3);
        if constexpr (PC < 3) {
            #pragma unroll
            for (int r = 0; r < NREG; ++r) {
                if (!((r >> PC) & 1)) continue;
                h2 p = lxor_h<LM>(st[r]);
                st[r] = pk_crx16(cs2, st[r], p);
            }
        } else {
            int apply = (tid >> (PC - 3)) & 1;
            h2 cse = apply ? cs2 : IDH;
            #pragma unroll
            for (int r = 0; r < NREG; ++r) {
                h2 p = lxor_h<LM>(st[r]);
                st[r] = pk_crx16(cse, st[r], p);
            }
        }
    }
}

__global__ __launch_bounds__(BLOCK)
void qfe_kernel(const float* __restrict__ params,
                const float* __restrict__ inputs,
                float* __restrict__ out) {
    const int b    = blockIdx.x;
    const int tid  = threadIdx.x;
    const int lane = tid & 63;

    __shared__ v2f buf[NREG * BLOCK];      // 32 KB: 2x16KB f16 ping-pong / f32 epilogue
    h2* bufh = (h2*)buf;
    __shared__ __align__(16) h2 mA[4 * 12 * 4];   // packed f16 matrices
    __shared__ __align__(16) h2 mB[4 * 11 * 4];
    __shared__ __align__(16) h2 mcrx[4 * 24];     // packed (cos,sin)
    __shared__ float  redbuf[32][36];             // epilogue row-partials; prologue cs table

    // parallel trig table (R18b). Aliases redbuf.
    float2* cs = (float2*)redbuf;
    if (tid < 240) {
        float a = params[b * NPARAM + tid] * 0.5f;
        cs[tid] = make_float2(cosf(a), sinf(a));
    } else if (tid < 252) {
        float e = inputs[b * NQ + (tid - 240)] * 0.5f;
        cs[tid] = make_float2(cosf(e), sinf(e));
    }
    __syncthreads();

    if (tid < 48) {
        int l = tid / 12, q = tid % 12;
        const float2 vx = cs[l * 60 + q * 3 + 0];
        const float2 vy = cs[l * 60 + q * 3 + 1];
        const float2 vz = cs[l * 60 + q * 3 + 2];
        float cx = vx.x, sx = vx.y;
        float cy = vy.x, sy = vy.y;
        float cz = vz.x, sz = vz.y;
        float2 a00 = make_float2( cy*cx,  sy*sx);
        float2 a01 = make_float2(-sy*cx, -cy*sx);
        float2 a10 = make_float2( sy*cx, -cy*sx);
        float2 a11 = make_float2( cy*cx, -sy*sx);
        float2 e0 = make_float2(cz, -sz);
        float2 e1 = make_float2(cz,  sz);
        float2 u00 = cmulf(e0, a00), u01 = cmulf(e0, a01);
        float2 u10 = cmulf(e1, a10), u11 = cmulf(e1, a11);
        if (l == 0) {   // fold RY input embedding
            float ce = cs[240 + q].x, se = cs[240 + q].y;
            float2 v00 = make_float2(u00.x*ce + u01.x*se, u00.y*ce + u01.y*se);
            float2 v01 = make_float2(-u00.x*se + u01.x*ce, -u00.y*se + u01.y*ce);
            float2 v10 = make_float2(u10.x*ce + u11.x*se, u10.y*ce + u11.y*se);
            float2 v11 = make_float2(-u10.x*se + u11.x*ce, -u10.y*se + u11.y*ce);
            u00 = v00; u01 = v01; u10 = v10; u11 = v11;
        }
        h2* m = &mA[(l * 12 + q) * 4];
        m[0] = packh2(u00.x, u00.y); m[1] = packh2(u01.x, u01.y);
        m[2] = packh2(u10.x, u10.y); m[3] = packh2(u11.x, u11.y);
    }
    if (tid >= 64 && tid < 160) {   // mcrx from cs table (independent of mA)
        int k2 = tid - 64;
        int l = k2 / 24, k = k2 % 24;
        float2 v = cs[l * 60 + 36 + k];
        mcrx[l * 24 + k] = packh2(v.x, v.y);
    }
    __syncthreads();
    if (tid < 44) {       // B(l,j) = RX(theta_ring1_j) * U(l, j+1)
        int l = tid / 11, j = tid % 11;
        const h2* U = &mA[(l * 12 + (j + 1)) * 4];
        v2f u00 = uph2(U[0]), u01 = uph2(U[1]), u10 = uph2(U[2]), u11 = uph2(U[3]);
        v2f csv = uph2(mcrx[l * 24 + j]);
        float c = csv.x, s = csv.y;
        h2* Bm = &mB[(l * 11 + j) * 4];
        Bm[0] = packh2( c*u00.x + s*u10.y,  c*u00.y - s*u10.x);
        Bm[1] = packh2( c*u01.x + s*u11.y,  c*u01.y - s*u11.x);
        Bm[2] = packh2( s*u00.y + c*u10.x, -s*u00.x + c*u10.y);
        Bm[3] = packh2( s*u01.y + c*u11.x, -s*u01.x + c*u11.y);
    }
    __syncthreads();

    h2 st[NREG];
    #pragma unroll
    for (int r = 0; r < NREG; ++r) st[r] = 0u;
    if (tid == 0) st[0] = IDH;            // |0..0> is map-independent

    const int rb41 = rbase<4,1>(tid);
    const int rb12 = rbase<1,2>(tid);
    const int rb23 = rbase<2,3>(tid);
    const int rb34 = rbase<3,4>(tid);

    #pragma unroll 1
    for (int l = 0; l < 4; ++l) {
        const h2* ma = mA + l * 48;
        const h2* mb = mB + l * 44;
        const h2* cl = mcrx + l * 24;
        // --- block A under M4: q2@0,q1@1,q0@2,q11@3,q4@4,q3@5 ---
        apply1q<2>(st, tid, ma + 0 * 4);                 // U(q0) @2
        fgate<2, 1>(st, tid, ma + 1 * 4, mb + 0 * 4);    // F(0,1)
        fgate<1, 0>(st, tid, ma + 2 * 4, mb + 1 * 4);    // F(1,2)
        fgate<0, 5>(st, tid, ma + 3 * 4, mb + 2 * 4);    // F(2,3) (swizzle)
        fgate<5, 4>(st, tid, ma + 4 * 4, mb + 3 * 4);    // F(3,4)
        remap<4, 1, 0>(st, tid, bufh, rb41);
        // --- block B under M1: q5@0,q6@1,q7@2,q8@3,q9@4; q4@6 ---
        fgate<6, 0>(st, tid, ma + 5 * 4, mb + 4 * 4);    // F(4,5)
        fgate<0, 1>(st, tid, ma + 6 * 4, mb + 5 * 4);    // F(5,6)
        fgate<1, 2>(st, tid, ma + 7 * 4, mb + 6 * 4);    // F(6,7)
        fgate<2, 3>(st, tid, ma + 8 * 4, mb + 7 * 4);    // F(7,8)
        fgate<3, 4>(st, tid, ma + 9 * 4, mb + 8 * 4);    // F(8,9)
        remap<1, 2, 1>(st, tid, bufh, rb12);
        // --- block C under M2: q10@0,q11@1,q0@2,q9@3,q8@4 ---
        fgate<3, 0>(st, tid, ma + 10 * 4, mb + 9 * 4);   // F(9,10)
        fgate<0, 1>(st, tid, ma + 11 * 4, mb + 10 * 4);  // F(10,11)
        applyCRX<1, 2>(st, tid, cl + 11);                // CRX(11,0)
        applyCRX<1, 0>(st, tid, cl + 12);                // ring2 (11,10)
        applyCRX<0, 3>(st, tid, cl + 13);                // (10,9)
        applyCRX<3, 4>(st, tid, cl + 14);                // (9,8)
        remap<2, 3, 0>(st, tid, bufh, rb23);
        // --- block D under M3: q7@0,q6@1,q5@2,q4@3,q3@4; q8@6 ---
        applyCRX<6, 0>(st, tid, cl + 15);                // (8,7)
        applyCRX<0, 1>(st, tid, cl + 16);                // (7,6)
        applyCRX<1, 2>(st, tid, cl + 17);                // (6,5)
        applyCRX<2, 3>(st, tid, cl + 18);                // (5,4)
        applyCRX<3, 4>(st, tid, cl + 19);                // (4,3)
        remap<3, 4, 1>(st, tid, bufh, rb34);
        // --- block E under M4: q2@0,q1@1,q0@2,q11@3; q3@5 ---
        applyCRX<5, 0>(st, tid, cl + 20);                // (3,2)
        applyCRX<0, 1>(st, tid, cl + 21);                // (2,1)
        applyCRX<1, 2>(st, tid, cl + 22);                // (1,0)
        applyCRX<2, 3>(st, tid, cl + 23);                // (0,11)
        // no remap: next layer's block A runs under M4
    }

    // ---- epilogue (f32) under M4 ----
    // pos->qubit: 0->2, 1->1, 2->0, 3->11, 4->4, 5->3, 6->9, 7->8, 8->10,
    //             9->5, 10->6, 11->7
    v2f stf[NREG];
    #pragma unroll
    for (int r = 0; r < NREG; ++r) stf[r] = uph2(st[r]);

    float nn[NREG];
    #pragma unroll
    for (int r = 0; r < NREG; ++r) nn[r] = stf[r].x*stf[r].x + stf[r].y*stf[r].y;
    float T  = ((nn[0]+nn[1])+(nn[2]+nn[3])) + ((nn[4]+nn[5])+(nn[6]+nn[7]));
    float Z0 = ((nn[0]-nn[1])+(nn[2]-nn[3])) + ((nn[4]-nn[5])+(nn[6]-nn[7]));
    float Z1 = ((nn[0]+nn[1])-(nn[2]+nn[3])) + ((nn[4]+nn[5])-(nn[6]+nn[7]));
    float Z2 = ((nn[0]+nn[1])+(nn[2]+nn[3])) - ((nn[4]+nn[5])+(nn[6]+nn[7]));

    __syncthreads();                       // WAR vs last remap reads + cs table
    #pragma unroll
    for (int r = 0; r < NREG; ++r) buf[r * BLOCK + tid] = stf[r];   // f32 layout
    __syncthreads();

    const int row16 = (tid >> 4);                 // 0..31: 16-lane row index
    const bool isred = (lane & 15) == 15;         // row-sum holder lane
    const float Tsum = wsum4(T);                  // shared row-sum of |psi|^2

#define EXP_REG(q, B, ZV) { \
    v2f acc = {0.f, 0.f}; \
    _Pragma("unroll") \
    for (int r = 0; r < NREG; ++r) { \
        if ((r >> (B)) & 1) continue; \
        acc = pk_cjmac(acc, stf[r], stf[r | (1 << (B))]); \
    } \
    float X = wsum4(2.f*acc.x), Y = wsum4(2.f*acc.y), Z = wsum4(ZV); \
    if (isred) { redbuf[row16][(q)] = X; redbuf[row16][12+(q)] = Y; redbuf[row16][24+(q)] = Z; } }

#define EXP_DPP(q, LM, TB) { \
    v2f acc = {0.f, 0.f}; \
    _Pragma("unroll") \
    for (int r = 0; r < NREG; ++r) { \
        v2f p = lxor2<LM>(stf[r]); \
        acc = pk_cjmac(acc, stf[r], p); \
    } \
    float zs = ((tid >> (TB)) & 1) ? -1.f : 1.f; \
    float X = wsum4(acc.x), Y = wsum4(zs*acc.y), Z = wsum4(zs*T); \
    if (isred) { redbuf[row16][(q)] = X; redbuf[row16][12+(q)] = Y; redbuf[row16][24+(q)] = Z; } }

// TB < 4: sign varies inside the 16-lane row -> full wsum4 on zs*T
#define EXP_BUF(q, XM, TB) { \
    v2f acc = {0.f, 0.f}; \
    int pt = tid ^ (XM); \
    _Pragma("unroll") \
    for (int r = 0; r < NREG; ++r) { \
        acc = pk_cjmac(acc, stf[r], buf[r * BLOCK + pt]); \
    } \
    float zs = ((tid >> (TB)) & 1) ? -1.f : 1.f; \
    float X = wsum4(acc.x), Y = wsum4(zs*acc.y), Z = wsum4(zs*T); \
    if (isred) { redbuf[row16][(q)] = X; redbuf[row16][12+(q)] = Y; redbuf[row16][24+(q)] = Z; } }

// TB >= 4: sign is row-uniform -> Z = zs * Tsum (no wsum4)
#define EXP_BUF_HI(q, XM, TB) { \
    v2f acc = {0.f, 0.f}; \
    int pt = tid ^ (XM); \
    _Pragma("unroll") \
    for (int r = 0; r < NREG; ++r) { \
        acc = pk_cjmac(acc, stf[r], buf[r * BLOCK + pt]); \
    } \
    float zs = ((tid >> (TB)) & 1) ? -1.f : 1.f; \
    float X = wsum4(acc.x), Y = wsum4(zs*acc.y), Z = zs * Tsum; \
    if (isred) { redbuf[row16][(q)] = X; redbuf[row16][12+(q)] = Y; redbuf[row16][24+(q)] = Z; } }

    EXP_REG(2, 0, Z0)  EXP_REG(1, 1, Z1)  EXP_REG(0, 2, Z2)
    EXP_DPP(11, 1, 0)  EXP_DPP(4, 2, 1)
    EXP_BUF(3, 4, 2)   EXP_BUF(9, 8, 3)
    EXP_BUF_HI(8, 16, 4)  EXP_BUF_HI(10, 32, 5)
    EXP_BUF_HI(5, 64, 6)  EXP_BUF_HI(6, 128, 7) EXP_BUF_HI(7, 256, 8)

    __syncthreads();
    if (tid < 36) {
        float acc = 0.f;
        #pragma unroll
        for (int i = 0; i < 32; ++i) acc += redbuf[i][tid];
        out[b * 36 + tid] = acc;
    }
}

extern "C" void kernel_launch(void* const* d_in, const int* in_sizes, int n_in,
                              void* d_out, int out_size, void* d_ws, size_t ws_size,
                              hipStream_t stream) {
    const float* params = (const float*)d_in[0];   // (1024, 240) float32
    const float* inputs = (const float*)d_in[1];   // (1024, 12)  float32
    float* out = (float*)d_out;                    // (1024, 36)  float32
    qfe_kernel<<<1024, BLOCK, 0, stream>>>(params, inputs, out);
}

// Round 8
// 105.389 us; speedup vs baseline: 1.0185x; 1.0001x over previous
//
#include <hip/hip_runtime.h>
#include <hip/hip_fp16.h>

#define NQ     12
#define NPARAM 240       // 12*4*5
#define BLOCK  512
#define NREG   8

typedef float v2f __attribute__((ext_vector_type(2)));
typedef unsigned int h2;     // packed f16 complex: lo=re, hi=im
#define IDH 0x00003C00u      // (1.0, 0.0) in packed f16

// ---- packed f16 complex primitives (v_pk_*_f16, full rate = 2x f32 flops) ----
__device__ __forceinline__ h2 pk_cmul16(h2 a, h2 b) {
    h2 t;
    asm("v_pk_mul_f16 %0, %1, %2 op_sel:[0,0] op_sel_hi:[0,1]\n\t"
        "v_pk_fma_f16 %0, %1, %2, %0 op_sel:[1,1,0] op_sel_hi:[1,0,1] neg_lo:[1,0,0]"
        : "=&v"(t) : "v"(a), "v"(b));
    return t;
}
__device__ __forceinline__ h2 pk_cmac16(h2 t0, h2 a, h2 b) {
    h2 t;
    asm("v_pk_fma_f16 %0, %2, %3, %1 op_sel:[0,0,0] op_sel_hi:[0,1,1]\n\t"
        "v_pk_fma_f16 %0, %2, %3, %0 op_sel:[1,1,0] op_sel_hi:[1,0,1] neg_lo:[1,0,0]"
        : "=&v"(t) : "v"(t0), "v"(a), "v"(b));
    return t;
}
// CRX halfstep: cs2=(c,s): lo = c*sx + s*py ; hi = c*sy - s*px
__device__ __forceinline__ h2 pk_crx16(h2 cs2, h2 s, h2 p) {
    h2 t;
    asm("v_pk_mul_f16 %0, %1, %2 op_sel:[0,0] op_sel_hi:[0,1]\n\t"
        "v_pk_fma_f16 %0, %1, %3, %0 op_sel:[1,1,0] op_sel_hi:[1,0,1] neg_hi:[0,1,0]"
        : "=&v"(t) : "v"(cs2), "v"(s), "v"(p));
    return t;
}
// f32 conj-accumulate for epilogue: acc += conj(s)(.)p
__device__ __forceinline__ v2f pk_cjmac(v2f a0, v2f s, v2f p) {
    v2f t;
    asm("v_pk_fma_f32 %0, %2, %3, %1 op_sel:[0,0,0] op_sel_hi:[0,1,1]\n\t"
        "v_pk_fma_f32 %0, %2, %3, %0 op_sel:[1,1,0] op_sel_hi:[1,0,1] neg_hi:[1,0,0]"
        : "=&v"(t) : "v"(a0), "v"(s), "v"(p));
    return t;
}

__device__ __forceinline__ h2 packh2(float x, float y) {
    return ((h2)__half_as_ushort(__float2half_rn(y)) << 16) |
           (h2)__half_as_ushort(__float2half_rn(x));
}
__device__ __forceinline__ v2f uph2(h2 u) {
    return (v2f){ __half2float(__ushort_as_half((unsigned short)(u & 0xffff))),
                  __half2float(__ushort_as_half((unsigned short)(u >> 16))) };
}

// Storage position p for a qubit:
//   p in [0,3)  -> register bit p of r       : pure VALU
//   p in [3,5)  -> lane bit (p-3), DPP       : pure VALU
//   p in [5,9)  -> lane bit (p-3)            : ds_swizzle / bpermute / buf
//   p in [9,12) -> tid bit (p-3) = wave bit  : ctrl-only (bit select)
// 4-map cycle M4 -> M1 -> M2 -> M3 -> M4 (16 remaps). Init/epilogue under M4.
//
// MODEL (calibrated R16/R6/R7): two cost currencies.
//  - VALU instrs: ~7 ns per instr/thread at this occupancy (144 instrs ~= 1 us).
//  - LDS-pipe ops (ds_swizzle/bpermute/read/write): second currency; R6's
//    +6 LDS-gates/layer cost +3.4 us.
//  - Remap barriers are CHEAP (~0.2 us each; 4-block/CU overlap hides them):
//    R6 removed 4 and saved <1 us; R17/18 stagger was null.
//  - Run-to-run noise ~= +-1.5 us (R5 vs R7, identical binaries).
// This 4-window schedule is minimal given <=6 targets/window and near-minimal
// LDS gate ops (16 reg + 8 DPP + 1 swizzle per layer). Bank conflicts ~2.1M
// are benign (R15). Do not re-litigate windows/stagger/swizzle.
//
// R21: (a) mB built directly in the U-pass from f32 values (removes 3rd
// prologue pass + 1 barrier + f16 round-trip); (b) packed (X,Y) epilogue
// reduction via v_pk_add_f32: 3 instrs/step vs 4 -> -48 instrs/thread.

constexpr int QMAP[5][12] = {
    // pos:   0   1   2   3   4    5   6   7   8    9  10  11
    /*M0*/ {  0,  1,  2,  3,  4,  10, 11,  9,  8,   5,  6,  7},   // unused
    /*M1*/ {  5,  6,  7,  8,  9,   3,  4, 10, 11,   0,  1,  2},
    /*M2*/ { 10, 11,  0,  9,  8,   3,  4,  5,  6,   1,  2,  7},
    /*M3*/ {  7,  6,  5,  4,  3,   9,  8, 10, 11,   0,  1,  2},
    /*M4*/ {  2,  1,  0, 11,  4,   3,  9,  8, 10,   5,  6,  7},
};

constexpr int posof(int m, int q) {
    for (int p = 0; p < 12; ++p) if (QMAP[m][p] == q) return p;
    return -1;
}
constexpr int ebit(int p) { return p < 3 ? 9 + p : p - 3; }
constexpr int roff(int MA, int MB, int r) {
    int off = 0;
    for (int p = 0; p < 3; ++p)
        off |= ((r >> p) & 1) << ebit(posof(MA, QMAP[MB][p]));
    return off;
}

template<int MA, int MB>
__device__ __forceinline__ int rbase(int tid) {
    int base = 0;
    #pragma unroll
    for (int p = 3; p < 12; ++p)
        base |= ((tid >> (p - 3)) & 1) << ebit(posof(MA, QMAP[MB][p]));
    return base;
}

// single-barrier ping-pong remap: PH selects the 16 KB half-buffer
template<int MA, int MB, int PH>
__device__ __forceinline__ void remap(h2* st, int tid, h2* bufh, int base) {
    h2* bp = bufh + PH * (NREG * BLOCK);
    #pragma unroll
    for (int r = 0; r < NREG; ++r) bp[r * BLOCK + tid] = st[r];
    __syncthreads();
    #pragma unroll
    for (int r = 0; r < NREG; ++r) st[r] = bp[base + roff(MA, MB, r)];
}

template<int LM>
__device__ __forceinline__ int lxori(int v) {
    if constexpr (LM == 1) {        // quad_perm [1,0,3,2] = xor 1, VALU pipe
        return __builtin_amdgcn_update_dpp(v, v, 0xB1, 0xF, 0xF, false);
    } else if constexpr (LM == 2) { // quad_perm [2,3,0,1] = xor 2, VALU pipe
        return __builtin_amdgcn_update_dpp(v, v, 0x4E, 0xF, 0xF, false);
    } else if constexpr (LM == 4) { // ds_swizzle BitMode xor-4, no addr VGPR
        return __builtin_amdgcn_ds_swizzle(v, 0x101F);
    } else if constexpr (LM == 8) {
        return __builtin_amdgcn_ds_swizzle(v, 0x201F);
    } else if constexpr (LM == 16) {
        return __builtin_amdgcn_ds_swizzle(v, 0x401F);
    } else {
        return __shfl_xor(v, LM, 64);
    }
}
template<int LM>
__device__ __forceinline__ h2 lxor_h(h2 v) { return (h2)lxori<LM>((int)v); }
template<int LM>
__device__ __forceinline__ v2f lxor2(v2f v) {
    v2f p = { __int_as_float(lxori<LM>(__float_as_int(v.x))),
              __int_as_float(lxori<LM>(__float_as_int(v.y))) };
    return p;
}

// truncated DPP reduction: 4 row_shr steps; lane 15 of each 16-lane row
// holds that row's sum. Cross-row + cross-wave handled via redbuf.
__device__ __forceinline__ float wsum4(float x) {
    x += __int_as_float(__builtin_amdgcn_update_dpp(0, __float_as_int(x), 0x111, 0xF, 0xF, true));
    x += __int_as_float(__builtin_amdgcn_update_dpp(0, __float_as_int(x), 0x112, 0xF, 0xF, true));
    x += __int_as_float(__builtin_amdgcn_update_dpp(0, __float_as_int(x), 0x114, 0xF, 0xF, true));
    x += __int_as_float(__builtin_amdgcn_update_dpp(0, __float_as_int(x), 0x118, 0xF, 0xF, true));
    return x;
}

// R21b: packed (X,Y) 16-lane reduction: 2 DPP movs + 1 v_pk_add_f32 per
// step (3 instrs vs 4 for two scalar wsum4 steps).
__device__ __forceinline__ v2f wsum4v(v2f x) {
#define WSTEP(C) { \
    v2f t; \
    t.x = __int_as_float(__builtin_amdgcn_update_dpp(0, __float_as_int(x.x), C, 0xF, 0xF, true)); \
    t.y = __int_as_float(__builtin_amdgcn_update_dpp(0, __float_as_int(x.y), C, 0xF, 0xF, true)); \
    asm("v_pk_add_f32 %0, %1, %2" : "=v"(x) : "v"(x), "v"(t)); }
    WSTEP(0x111) WSTEP(0x112) WSTEP(0x114) WSTEP(0x118)
#undef WSTEP
    return x;
}

__device__ __forceinline__ float2 cmulf(float2 a, float2 b) {
    return make_float2(a.x*b.x - a.y*b.y, a.x*b.y + a.y*b.x);
}

// plain 1q gate at position P
template<int P>
__device__ __forceinline__ void apply1q(h2* st, int tid, const h2* m) {
    h2 u00 = m[0], u01 = m[1], u10 = m[2], u11 = m[3];
    if constexpr (P < 3) {
        #pragma unroll
        for (int r = 0; r < NREG; ++r) {
            if ((r >> P) & 1) continue;
            int r1 = r | (1 << P);
            h2 s0 = st[r], s1 = st[r1];
            st[r]  = pk_cmac16(pk_cmul16(u00, s0), u01, s1);
            st[r1] = pk_cmac16(pk_cmul16(u10, s0), u11, s1);
        }
    } else {
        constexpr int LM = 1 << (P - 3);
        int bit = (tid >> (P - 3)) & 1;
        h2 d = bit ? u11 : u00;
        h2 o = bit ? u10 : u01;
        #pragma unroll
        for (int r = 0; r < NREG; ++r) {
            h2 p = lxor_h<LM>(st[r]);
            st[r] = pk_cmac16(pk_cmul16(d, st[r]), o, p);
        }
    }
}

// fused ring1 gate: A (ctrl=0) / B = RX*A (ctrl=1)
template<int PC, int PT>
__device__ __forceinline__ void fgate(h2* st, int tid, const h2* A, const h2* B) {
    h2 a00 = A[0], a01 = A[1], a10 = A[2], a11 = A[3];
    h2 b00 = B[0], b01 = B[1], b10 = B[2], b11 = B[3];
    if constexpr (PT < 3) {
        if constexpr (PC < 3) {
            #pragma unroll
            for (int r = 0; r < NREG; ++r) {
                if ((r >> PT) & 1) continue;
                const bool uB = (r >> PC) & 1;               // compile-time
                h2 m00 = uB ? b00 : a00, m01 = uB ? b01 : a01;
                h2 m10 = uB ? b10 : a10, m11 = uB ? b11 : a11;
                int r1 = r | (1 << PT);
                h2 s0 = st[r], s1 = st[r1];
                st[r]  = pk_cmac16(pk_cmul16(m00, s0), m01, s1);
                st[r1] = pk_cmac16(pk_cmul16(m10, s0), m11, s1);
            }
        } else {
            int cbit = (tid >> (PC - 3)) & 1;
            h2 m00 = cbit ? b00 : a00, m01 = cbit ? b01 : a01;
            h2 m10 = cbit ? b10 : a10, m11 = cbit ? b11 : a11;
            #pragma unroll
            for (int r = 0; r < NREG; ++r) {
                if ((r >> PT) & 1) continue;
                int r1 = r | (1 << PT);
                h2 s0 = st[r], s1 = st[r1];
                st[r]  = pk_cmac16(pk_cmul16(m00, s0), m01, s1);
                st[r1] = pk_cmac16(pk_cmul16(m10, s0), m11, s1);
            }
        }
    } else {
        constexpr int LM = 1 << (PT - 3);
        int tbit = (tid >> (PT - 3)) & 1;
        h2 dA = tbit ? a11 : a00, oA = tbit ? a10 : a01;
        h2 dB = tbit ? b11 : b00, oB = tbit ? b10 : b01;
        if constexpr (PC < 3) {
            #pragma unroll
            for (int r = 0; r < NREG; ++r) {
                const bool uB = (r >> PC) & 1;               // compile-time
                h2 d = uB ? dB : dA, o = uB ? oB : oA;
                h2 p = lxor_h<LM>(st[r]);
                st[r] = pk_cmac16(pk_cmul16(d, st[r]), o, p);
            }
        } else {
            int cbit = (tid >> (PC - 3)) & 1;
            h2 d = cbit ? dB : dA, o = cbit ? oB : oA;
            #pragma unroll
            for (int r = 0; r < NREG; ++r) {
                h2 p = lxor_h<LM>(st[r]);
                st[r] = pk_cmac16(pk_cmul16(d, st[r]), o, p);
            }
        }
    }
}

// CRX(ctrl at PC, tgt at PT)
template<int PC, int PT>
__device__ __forceinline__ void applyCRX(h2* st, int tid, const h2* cs) {
    h2 cs2 = cs[0];                      // packed (cos, sin)
    if constexpr (PT < 3) {
        if constexpr (PC < 3) {
            #pragma unroll
            for (int r = 0; r < NREG; ++r) {
                if (!((r >> PC) & 1) || ((r >> PT) & 1)) continue;
                int r1 = r | (1 << PT);
                h2 s0 = st[r], s1 = st[r1];
                st[r]  = pk_crx16(cs2, s0, s1);
                st[r1] = pk_crx16(cs2, s1, s0);
            }
        } else {
            int apply = (tid >> (PC - 3)) & 1;
            h2 cse = apply ? cs2 : IDH;
            #pragma unroll
            for (int r = 0; r < NREG; ++r) {
                if ((r >> PT) & 1) continue;
                int r1 = r | (1 << PT);
                h2 s0 = st[r], s1 = st[r1];
                st[r]  = pk_crx16(cse, s0, s1);
                st[r1] = pk_crx16(cse, s1, s0);
            }
        }
    } else {
        constexpr int LM = 1 << (PT - 3);
        if constexpr (PC < 3) {
            #pragma unroll
            for (int r = 0; r < NREG; ++r) {
                if (!((r >> PC) & 1)) continue;
                h2 p = lxor_h<LM>(st[r]);
                st[r] = pk_crx16(cs2, st[r], p);
            }
        } else {
            int apply = (tid >> (PC - 3)) & 1;
            h2 cse = apply ? cs2 : IDH;
            #pragma unroll
            for (int r = 0; r < NREG; ++r) {
                h2 p = lxor_h<LM>(st[r]);
                st[r] = pk_crx16(cse, st[r], p);
            }
        }
    }
}

__global__ __launch_bounds__(BLOCK)
void qfe_kernel(const float* __restrict__ params,
                const float* __restrict__ inputs,
                float* __restrict__ out) {
    const int b    = blockIdx.x;
    const int tid  = threadIdx.x;
    const int lane = tid & 63;

    __shared__ v2f buf[NREG * BLOCK];      // 32 KB: 2x16KB f16 ping-pong / f32 epilogue
    h2* bufh = (h2*)buf;
    __shared__ __align__(16) h2 mA[4 * 12 * 4];   // packed f16 matrices
    __shared__ __align__(16) h2 mB[4 * 11 * 4];
    __shared__ __align__(16) h2 mcrx[4 * 24];     // packed (cos,sin)
    __shared__ float  redbuf[32][36];             // epilogue row-partials; prologue cs table

    // parallel trig table. Aliases redbuf (252*8 B <= 4608 B).
    float2* cs = (float2*)redbuf;
    if (tid < 240) {
        float a = params[b * NPARAM + tid] * 0.5f;
        cs[tid] = make_float2(cosf(a), sinf(a));
    } else if (tid < 252) {
        float e = inputs[b * NQ + (tid - 240)] * 0.5f;
        cs[tid] = make_float2(cosf(e), sinf(e));
    }
    __syncthreads();

    if (tid < 48) {
        int l = tid / 12, q = tid % 12;
        const float2 vx = cs[l * 60 + q * 3 + 0];
        const float2 vy = cs[l * 60 + q * 3 + 1];
        const float2 vz = cs[l * 60 + q * 3 + 2];
        float cx = vx.x, sx = vx.y;
        float cy = vy.x, sy = vy.y;
        float cz = vz.x, sz = vz.y;
        float2 a00 = make_float2( cy*cx,  sy*sx);
        float2 a01 = make_float2(-sy*cx, -cy*sx);
        float2 a10 = make_float2( sy*cx, -cy*sx);
        float2 a11 = make_float2( cy*cx, -sy*sx);
        float2 e0 = make_float2(cz, -sz);
        float2 e1 = make_float2(cz,  sz);
        float2 u00 = cmulf(e0, a00), u01 = cmulf(e0, a01);
        float2 u10 = cmulf(e1, a10), u11 = cmulf(e1, a11);
        if (l == 0) {   // fold RY input embedding
            float ce = cs[240 + q].x, se = cs[240 + q].y;
            float2 v00 = make_float2(u00.x*ce + u01.x*se, u00.y*ce + u01.y*se);
            float2 v01 = make_float2(-u00.x*se + u01.x*ce, -u00.y*se + u01.y*ce);
            float2 v10 = make_float2(u10.x*ce + u11.x*se, u10.y*ce + u11.y*se);
            float2 v11 = make_float2(-u10.x*se + u11.x*ce, -u10.y*se + u11.y*ce);
            u00 = v00; u01 = v01; u10 = v10; u11 = v11;
        }
        h2* m = &mA[(l * 12 + q) * 4];
        m[0] = packh2(u00.x, u00.y); m[1] = packh2(u01.x, u01.y);
        m[2] = packh2(u10.x, u10.y); m[3] = packh2(u11.x, u11.y);
        if (q >= 1) {   // R21a: mB(l,q-1) = RX(ring1_{q-1}) * U(l,q), f32 src
            float2 csv = cs[l * 60 + 36 + (q - 1)];
            float c = csv.x, s = csv.y;
            h2* Bm = &mB[(l * 11 + (q - 1)) * 4];
            Bm[0] = packh2( c*u00.x + s*u10.y,  c*u00.y - s*u10.x);
            Bm[1] = packh2( c*u01.x + s*u11.y,  c*u01.y - s*u11.x);
            Bm[2] = packh2( s*u00.y + c*u10.x, -s*u00.x + c*u10.y);
            Bm[3] = packh2( s*u01.y + c*u11.x, -s*u01.x + c*u11.y);
        }
    }
    if (tid >= 64 && tid < 160) {   // mcrx from cs table (independent of mA)
        int k2 = tid - 64;
        int l = k2 / 24, k = k2 % 24;
        float2 v = cs[l * 60 + 36 + k];
        mcrx[l * 24 + k] = packh2(v.x, v.y);
    }
    __syncthreads();

    h2 st[NREG];
    #pragma unroll
    for (int r = 0; r < NREG; ++r) st[r] = 0u;
    if (tid == 0) st[0] = IDH;            // |0..0> is map-independent

    const int rb41 = rbase<4,1>(tid);
    const int rb12 = rbase<1,2>(tid);
    const int rb23 = rbase<2,3>(tid);
    const int rb34 = rbase<3,4>(tid);

    #pragma unroll 1
    for (int l = 0; l < 4; ++l) {
        const h2* ma = mA + l * 48;
        const h2* mb = mB + l * 44;
        const h2* cl = mcrx + l * 24;
        // --- block A under M4: q2@0,q1@1,q0@2,q11@3,q4@4,q3@5 ---
        apply1q<2>(st, tid, ma + 0 * 4);                 // U(q0) @2
        fgate<2, 1>(st, tid, ma + 1 * 4, mb + 0 * 4);    // F(0,1)
        fgate<1, 0>(st, tid, ma + 2 * 4, mb + 1 * 4);    // F(1,2)
        fgate<0, 5>(st, tid, ma + 3 * 4, mb + 2 * 4);    // F(2,3) (swizzle)
        fgate<5, 4>(st, tid, ma + 4 * 4, mb + 3 * 4);    // F(3,4)
        remap<4, 1, 0>(st, tid, bufh, rb41);
        // --- block B under M1: q5@0,q6@1,q7@2,q8@3,q9@4; q4@6 ---
        fgate<6, 0>(st, tid, ma + 5 * 4, mb + 4 * 4);    // F(4,5)
        fgate<0, 1>(st, tid, ma + 6 * 4, mb + 5 * 4);    // F(5,6)
        fgate<1, 2>(st, tid, ma + 7 * 4, mb + 6 * 4);    // F(6,7)
        fgate<2, 3>(st, tid, ma + 8 * 4, mb + 7 * 4);    // F(7,8)
        fgate<3, 4>(st, tid, ma + 9 * 4, mb + 8 * 4);    // F(8,9)
        remap<1, 2, 1>(st, tid, bufh, rb12);
        // --- block C under M2: q10@0,q11@1,q0@2,q9@3,q8@4 ---
        fgate<3, 0>(st, tid, ma + 10 * 4, mb + 9 * 4);   // F(9,10)
        fgate<0, 1>(st, tid, ma + 11 * 4, mb + 10 * 4);  // F(10,11)
        applyCRX<1, 2>(st, tid, cl + 11);                // CRX(11,0)
        applyCRX<1, 0>(st, tid, cl + 12);                // ring2 (11,10)
        applyCRX<0, 3>(st, tid, cl + 13);                // (10,9)
        applyCRX<3, 4>(st, tid, cl + 14);                // (9,8)
        remap<2, 3, 0>(st, tid, bufh, rb23);
        // --- block D under M3: q7@0,q6@1,q5@2,q4@3,q3@4; q8@6 ---
        applyCRX<6, 0>(st, tid, cl + 15);                // (8,7)
        applyCRX<0, 1>(st, tid, cl + 16);                // (7,6)
        applyCRX<1, 2>(st, tid, cl + 17);                // (6,5)
        applyCRX<2, 3>(st, tid, cl + 18);                // (5,4)
        applyCRX<3, 4>(st, tid, cl + 19);                // (4,3)
        remap<3, 4, 1>(st, tid, bufh, rb34);
        // --- block E under M4: q2@0,q1@1,q0@2,q11@3; q3@5 ---
        applyCRX<5, 0>(st, tid, cl + 20);                // (3,2)
        applyCRX<0, 1>(st, tid, cl + 21);                // (2,1)
        applyCRX<1, 2>(st, tid, cl + 22);                // (1,0)
        applyCRX<2, 3>(st, tid, cl + 23);                // (0,11)
        // no remap: next layer's block A runs under M4
    }

    // ---- epilogue (f32) under M4 ----
    // pos->qubit: 0->2, 1->1, 2->0, 3->11, 4->4, 5->3, 6->9, 7->8, 8->10,
    //             9->5, 10->6, 11->7
    v2f stf[NREG];
    #pragma unroll
    for (int r = 0; r < NREG; ++r) stf[r] = uph2(st[r]);

    float nn[NREG];
    #pragma unroll
    for (int r = 0; r < NREG; ++r) nn[r] = stf[r].x*stf[r].x + stf[r].y*stf[r].y;
    float T  = ((nn[0]+nn[1])+(nn[2]+nn[3])) + ((nn[4]+nn[5])+(nn[6]+nn[7]));
    float Z0 = ((nn[0]-nn[1])+(nn[2]-nn[3])) + ((nn[4]-nn[5])+(nn[6]-nn[7]));
    float Z1 = ((nn[0]+nn[1])-(nn[2]+nn[3])) + ((nn[4]+nn[5])-(nn[6]+nn[7]));
    float Z2 = ((nn[0]+nn[1])+(nn[2]+nn[3])) - ((nn[4]+nn[5])+(nn[6]+nn[7]));

    __syncthreads();                       // WAR vs last remap reads + cs table
    #pragma unroll
    for (int r = 0; r < NREG; ++r) buf[r * BLOCK + tid] = stf[r];   // f32 layout
    __syncthreads();

    const int row16 = (tid >> 4);                 // 0..31: 16-lane row index
    const bool isred = (lane & 15) == 15;         // row-sum holder lane
    const float Tsum = wsum4(T);                  // shared row-sum of |psi|^2

#define EXP_REG(q, B, ZV) { \
    v2f acc = {0.f, 0.f}; \
    _Pragma("unroll") \
    for (int r = 0; r < NREG; ++r) { \
        if ((r >> (B)) & 1) continue; \
        acc = pk_cjmac(acc, stf[r], stf[r | (1 << (B))]); \
    } \
    v2f xy = wsum4v((v2f){2.f*acc.x, 2.f*acc.y}); \
    float Z = wsum4(ZV); \
    if (isred) { redbuf[row16][(q)] = xy.x; redbuf[row16][12+(q)] = xy.y; redbuf[row16][24+(q)] = Z; } }

#define EXP_DPP(q, LM, TB) { \
    v2f acc = {0.f, 0.f}; \
    _Pragma("unroll") \
    for (int r = 0; r < NREG; ++r) { \
        v2f p = lxor2<LM>(stf[r]); \
        acc = pk_cjmac(acc, stf[r], p); \
    } \
    float zs = ((tid >> (TB)) & 1) ? -1.f : 1.f; \
    v2f xy = wsum4v((v2f){acc.x, zs*acc.y}); \
    float Z = wsum4(zs*T); \
    if (isred) { redbuf[row16][(q)] = xy.x; redbuf[row16][12+(q)] = xy.y; redbuf[row16][24+(q)] = Z; } }

// TB < 4: sign varies inside the 16-lane row -> full wsum4 on zs*T
#define EXP_BUF(q, XM, TB) { \
    v2f acc = {0.f, 0.f}; \
    int pt = tid ^ (XM); \
    _Pragma("unroll") \
    for (int r = 0; r < NREG; ++r) { \
        acc = pk_cjmac(acc, stf[r], buf[r * BLOCK + pt]); \
    } \
    float zs = ((tid >> (TB)) & 1) ? -1.f : 1.f; \
    v2f xy = wsum4v((v2f){acc.x, zs*acc.y}); \
    float Z = wsum4(zs*T); \
    if (isred) { redbuf[row16][(q)] = xy.x; redbuf[row16][12+(q)] = xy.y; redbuf[row16][24+(q)] = Z; } }

// TB >= 4: sign is row-uniform -> Z = zs * Tsum (no wsum4)
#define EXP_BUF_HI(q, XM, TB) { \
    v2f acc = {0.f, 0.f}; \
    int pt = tid ^ (XM); \
    _Pragma("unroll") \
    for (int r = 0; r < NREG; ++r) { \
        acc = pk_cjmac(acc, stf[r], buf[r * BLOCK + pt]); \
    } \
    float zs = ((tid >> (TB)) & 1) ? -1.f : 1.f; \
    v2f xy = wsum4v((v2f){acc.x, zs*acc.y}); \
    float Z = zs * Tsum; \
    if (isred) { redbuf[row16][(q)] = xy.x; redbuf[row16][12+(q)] = xy.y; redbuf[row16][24+(q)] = Z; } }

    EXP_REG(2, 0, Z0)  EXP_REG(1, 1, Z1)  EXP_REG(0, 2, Z2)
    EXP_DPP(11, 1, 0)  EXP_DPP(4, 2, 1)
    EXP_BUF(3, 4, 2)   EXP_BUF(9, 8, 3)
    EXP_BUF_HI(8, 16, 4)  EXP_BUF_HI(10, 32, 5)
    EXP_BUF_HI(5, 64, 6)  EXP_BUF_HI(6, 128, 7) EXP_BUF_HI(7, 256, 8)

    __syncthreads();
    if (tid < 36) {
        float acc = 0.f;
        #pragma unroll
        for (int i = 0; i < 32; ++i) acc += redbuf[i][tid];
        out[b * 36 + tid] = acc;
    }
}

extern "C" void kernel_launch(void* const* d_in, const int* in_sizes, int n_in,
                              void* d_out, int out_size, void* d_ws, size_t ws_size,
                              hipStream_t stream) {
    const float* params = (const float*)d_in[0];   // (1024, 240) float32
    const float* inputs = (const float*)d_in[1];   // (1024, 12)  float32
    float* out = (float*)d_out;                    // (1024, 36)  float32
    qfe_kernel<<<1024, BLOCK, 0, stream>>>(params, inputs, out);
}